// Round 2
// baseline (249.422 us; speedup 1.0000x reference)
//
#include <hip/hip_runtime.h>

#define HID 128
#define PROW 104   // P row: src-half at [0..49], dst-half at [52..101] (16B-aligned halves)

// ---------- detect int32 vs int64 edge_index layout ----------
__global__ void detect_idx_kernel(const unsigned int* __restrict__ p, int* __restrict__ flag) {
  __shared__ int s;
  if (threadIdx.x == 0) s = 0;
  __syncthreads();
  // int64 values < 50000 -> all high words zero; int32 real indices -> ~never all zero
  if (p[2 * threadIdx.x + 1] != 0u) atomicOr(&s, 1);
  __syncthreads();
  if (threadIdx.x == 0) *flag = s;   // 1 -> int32 layout, 0 -> int64 layout
}

// ---------- node precompute: P[n][half*52+j] = relu(x[n]) @ W1[half*128 .. +127][j] ----------
__global__ __launch_bounds__(256, 4)
void node_pre_kernel(const float* __restrict__ x, const float* __restrict__ W1,
                     float* __restrict__ P, int n_nodes) {
  __shared__ __align__(16) float a_s[32][132];   // transposed [k][node], pad 132 for banks+align
  __shared__ __align__(16) float w_s[32][64];
  const int t = threadIdx.x;
  const int half = blockIdx.y;
  const int n0 = blockIdx.x * 128;
  const int jt = t & 15, rt = t >> 4;
  float acc[8][4];
#pragma unroll
  for (int i = 0; i < 8; ++i)
#pragma unroll
    for (int q = 0; q < 4; ++q) acc[i][q] = 0.f;

  for (int kc = 0; kc < 4; ++kc) {
#pragma unroll
    for (int i = 0; i < 4; ++i) {
      int f = t + 256 * i;            // 1024 float4 = 128 rows x 32 k
      int e = f >> 3;
      int k4 = (f & 7) << 2;
      int n = n0 + e;
      float4 v = make_float4(0.f, 0.f, 0.f, 0.f);
      if (n < n_nodes) v = *(const float4*)&x[(long)n * HID + kc * 32 + k4];
      a_s[k4 + 0][e] = fmaxf(v.x, 0.f);
      a_s[k4 + 1][e] = fmaxf(v.y, 0.f);
      a_s[k4 + 2][e] = fmaxf(v.z, 0.f);
      a_s[k4 + 3][e] = fmaxf(v.w, 0.f);
    }
#pragma unroll
    for (int i = 0; i < 8; ++i) {
      int f = t + 256 * i;            // 2048 = 32 k x 64 j
      int k = f >> 6, j = f & 63;
      float w = 0.f;
      if (j < 50) w = W1[(half * 128 + kc * 32 + k) * 50 + j];
      w_s[k][j] = w;
    }
    __syncthreads();
#pragma unroll 8
    for (int kk = 0; kk < 32; ++kk) {
      float4 w4 = *(const float4*)&w_s[kk][jt * 4];
      float4 a0 = *(const float4*)&a_s[kk][rt * 8];
      float4 a1 = *(const float4*)&a_s[kk][rt * 8 + 4];
      float av[8] = {a0.x, a0.y, a0.z, a0.w, a1.x, a1.y, a1.z, a1.w};
      float wv[4] = {w4.x, w4.y, w4.z, w4.w};
#pragma unroll
      for (int ri = 0; ri < 8; ++ri)
#pragma unroll
        for (int q = 0; q < 4; ++q) acc[ri][q] = fmaf(av[ri], wv[q], acc[ri][q]);
    }
    __syncthreads();
  }
  int jb = jt * 4;
  if (jb < 50) {
#pragma unroll
    for (int ri = 0; ri < 8; ++ri) {
      int n = n0 + rt * 8 + ri;
      if (n < n_nodes) {
#pragma unroll
        for (int q = 0; q < 4; ++q) {
          int j = jb + q;
          if (j < 50) P[(long)n * PROW + half * 52 + j] = acc[ri][q];
        }
      }
    }
  }
}

// ---------- fused edge kernel: ea@W1c + gather(P) + bias/relu + MLP layers 2,3 ----------
__global__ __launch_bounds__(256, 4)
void edge_kernel(const float* __restrict__ ea, const void* __restrict__ eidx,
                 const float* __restrict__ W1, const float* __restrict__ b1,
                 const float* __restrict__ W2, const float* __restrict__ b2,
                 const float* __restrict__ W3, const float* __restrict__ b3,
                 const float* __restrict__ P, const int* __restrict__ flag,
                 float* __restrict__ out, int n_edges) {
  __shared__ __align__(16) union SU {
    struct { float a[32][132]; float w[32][64]; } s1;  // GEMM staging (25 KB)
    float h1[128][53];                                  // layer-1 output (27.1 KB)
  } u;
  __shared__ float w2_s[50][25];
  __shared__ float w3_s[25];
  __shared__ float b1_s[64];
  __shared__ float b2_s[25];
  __shared__ float p_s[2][128];
  __shared__ int src_s[128], dst_s[128];

  const int t = threadIdx.x;
  const int e0 = blockIdx.x * 128;

  for (int f = t; f < 1250; f += 256) ((float*)w2_s)[f] = W2[f];
  if (t < 25) { w3_s[t] = W3[t]; b2_s[t] = b2[t]; }
  if (t < 64) b1_s[t] = (t < 50) ? b1[t] : 0.f;
  const int use32 = *flag;
  if (t < 128) {
    int e = e0 + t;
    int v = 0;
    if (e < n_edges) v = use32 ? ((const int*)eidx)[e] : (int)((const long long*)eidx)[e];
    src_s[t] = v;
  } else {
    int e = e0 + (t - 128);
    int v = 0;
    if (e < n_edges)
      v = use32 ? ((const int*)eidx)[(long)n_edges + e] : (int)((const long long*)eidx)[(long)n_edges + e];
    dst_s[t - 128] = v;
  }

  const int jt = t & 15, rt = t >> 4;
  float acc[8][4];
#pragma unroll
  for (int i = 0; i < 8; ++i)
#pragma unroll
    for (int q = 0; q < 4; ++q) acc[i][q] = 0.f;

  for (int kc = 0; kc < 4; ++kc) {
#pragma unroll
    for (int i = 0; i < 4; ++i) {
      int f = t + 256 * i;
      int e = f >> 3;
      int k4 = (f & 7) << 2;
      int ee = e0 + e;
      float4 v = make_float4(0.f, 0.f, 0.f, 0.f);
      if (ee < n_edges) v = *(const float4*)&ea[(long)ee * HID + kc * 32 + k4];
      u.s1.a[k4 + 0][e] = v.x;
      u.s1.a[k4 + 1][e] = v.y;
      u.s1.a[k4 + 2][e] = v.z;
      u.s1.a[k4 + 3][e] = v.w;
    }
#pragma unroll
    for (int i = 0; i < 8; ++i) {
      int f = t + 256 * i;
      int k = f >> 6, j = f & 63;
      float w = 0.f;
      if (j < 50) w = W1[(256 + kc * 32 + k) * 50 + j];
      u.s1.w[k][j] = w;
    }
    __syncthreads();
#pragma unroll 8
    for (int kk = 0; kk < 32; ++kk) {
      float4 w4 = *(const float4*)&u.s1.w[kk][jt * 4];
      float4 a0 = *(const float4*)&u.s1.a[kk][rt * 8];
      float4 a1 = *(const float4*)&u.s1.a[kk][rt * 8 + 4];
      float av[8] = {a0.x, a0.y, a0.z, a0.w, a1.x, a1.y, a1.z, a1.w};
      float wv[4] = {w4.x, w4.y, w4.z, w4.w};
#pragma unroll
      for (int ri = 0; ri < 8; ++ri)
#pragma unroll
        for (int q = 0; q < 4; ++q) acc[ri][q] = fmaf(av[ri], wv[q], acc[ri][q]);
    }
    __syncthreads();
  }

  // layer-1 epilogue: gather node terms, bias, relu -> h1 (overwrites staging union; safe after sync)
  int jb = jt * 4;
  if (jb < 50) {
#pragma unroll
    for (int ri = 0; ri < 8; ++ri) {
      int e = rt * 8 + ri;
      int s = src_s[e], d = dst_s[e];
      float4 pa = *(const float4*)&P[(long)s * PROW + jb];
      float4 pb = *(const float4*)&P[(long)d * PROW + 52 + jb];
      float par[4] = {pa.x, pa.y, pa.z, pa.w};
      float pbr[4] = {pb.x, pb.y, pb.z, pb.w};
#pragma unroll
      for (int q = 0; q < 4; ++q) {
        int j = jb + q;
        if (j < 50) {
          float v = acc[ri][q] + par[q] + pbr[q] + b1_s[j];
          u.h1[e][j] = fmaxf(v, 0.f);
        }
      }
    }
  }
  __syncthreads();

  // layers 2 + 3: two threads per edge, 13/12 columns each
  const int e2 = t & 127, hh = t >> 7;
  const int jb2 = hh * 13;
  float acc2[13];
#pragma unroll
  for (int jj = 0; jj < 13; ++jj) {
    int j2 = jb2 + jj;
    acc2[jj] = (j2 < 25) ? b2_s[j2] : 0.f;
  }
  for (int k2 = 0; k2 < 50; ++k2) {
    float v = u.h1[e2][k2];
#pragma unroll
    for (int jj = 0; jj < 13; ++jj) {
      int j2 = jb2 + jj;
      if (j2 < 25) acc2[jj] = fmaf(v, w2_s[k2][j2], acc2[jj]);
    }
  }
  float part = 0.f;
#pragma unroll
  for (int jj = 0; jj < 13; ++jj) {
    int j2 = jb2 + jj;
    if (j2 < 25) part += fmaxf(acc2[jj], 0.f) * w3_s[j2];
  }
  p_s[hh][e2] = part;
  __syncthreads();
  if (t < 128 && (e0 + t) < n_edges) out[e0 + t] = p_s[0][t] + p_s[1][t] + b3[0];
}

// ---------- naive fallback (only if ws too small for P) ----------
__global__ __launch_bounds__(256, 2)
void edge_naive_kernel(const float* __restrict__ x, const float* __restrict__ ea,
                       const void* __restrict__ eidx,
                       const float* __restrict__ W1, const float* __restrict__ b1,
                       const float* __restrict__ W2, const float* __restrict__ b2,
                       const float* __restrict__ W3, const float* __restrict__ b3,
                       const int* __restrict__ flag, int use32_const,
                       float* __restrict__ out, int n_edges) {
  int e = blockIdx.x * blockDim.x + threadIdx.x;
  if (e >= n_edges) return;
  int use32 = flag ? *flag : use32_const;
  long s, d;
  if (use32) {
    s = ((const int*)eidx)[e];
    d = ((const int*)eidx)[(long)n_edges + e];
  } else {
    s = (long)((const long long*)eidx)[e];
    d = (long)((const long long*)eidx)[(long)n_edges + e];
  }
  float h1[50];
#pragma unroll
  for (int j = 0; j < 50; ++j) h1[j] = b1[j];
  for (int k = 0; k < 128; ++k) {
    float v = fmaxf(x[s * HID + k], 0.f);
#pragma unroll
    for (int j = 0; j < 50; ++j) h1[j] = fmaf(v, W1[k * 50 + j], h1[j]);
  }
  for (int k = 0; k < 128; ++k) {
    float v = fmaxf(x[d * HID + k], 0.f);
#pragma unroll
    for (int j = 0; j < 50; ++j) h1[j] = fmaf(v, W1[(128 + k) * 50 + j], h1[j]);
  }
  for (int k = 0; k < 128; ++k) {
    float v = ea[(long)e * HID + k];
#pragma unroll
    for (int j = 0; j < 50; ++j) h1[j] = fmaf(v, W1[(256 + k) * 50 + j], h1[j]);
  }
  float o = b3[0];
  for (int j2 = 0; j2 < 25; ++j2) {
    float h2 = b2[j2];
#pragma unroll 10
    for (int k = 0; k < 50; ++k) h2 = fmaf(fmaxf(h1[k], 0.f), W2[k * 25 + j2], h2);
    o = fmaf(fmaxf(h2, 0.f), W3[j2], o);
  }
  out[e] = o;
}

extern "C" void kernel_launch(void* const* d_in, const int* in_sizes, int n_in,
                              void* d_out, int out_size, void* d_ws, size_t ws_size,
                              hipStream_t stream) {
  const float* x  = (const float*)d_in[0];
  const float* ea = (const float*)d_in[1];
  const void*  ei = d_in[2];
  const float* W1 = (const float*)d_in[3];
  const float* b1 = (const float*)d_in[4];
  const float* W2 = (const float*)d_in[5];
  const float* b2 = (const float*)d_in[6];
  const float* W3 = (const float*)d_in[7];
  const float* b3 = (const float*)d_in[8];
  float* out = (float*)d_out;
  const int n_nodes = in_sizes[0] / HID;
  const int n_edges = in_sizes[1] / HID;
  const size_t pbytes = (size_t)n_nodes * PROW * sizeof(float);

  if (ws_size >= pbytes + sizeof(int)) {
    float* P = (float*)d_ws;
    int* flag = (int*)((char*)d_ws + pbytes);
    hipLaunchKernelGGL(detect_idx_kernel, dim3(1), dim3(256), 0, stream,
                       (const unsigned int*)ei, flag);
    dim3 gp((n_nodes + 127) / 128, 2);
    hipLaunchKernelGGL(node_pre_kernel, gp, dim3(256), 0, stream, x, W1, P, n_nodes);
    dim3 ge((n_edges + 127) / 128);
    hipLaunchKernelGGL(edge_kernel, ge, dim3(256), 0, stream,
                       ea, ei, W1, b1, W2, b2, W3, b3, P, flag, out, n_edges);
  } else if (ws_size >= sizeof(int)) {
    int* flag = (int*)d_ws;
    hipLaunchKernelGGL(detect_idx_kernel, dim3(1), dim3(256), 0, stream,
                       (const unsigned int*)ei, flag);
    hipLaunchKernelGGL(edge_naive_kernel, dim3((n_edges + 255) / 256), dim3(256), 0, stream,
                       x, ea, ei, W1, b1, W2, b2, W3, b3, flag, 1, out, n_edges);
  } else {
    hipLaunchKernelGGL(edge_naive_kernel, dim3((n_edges + 255) / 256), dim3(256), 0, stream,
                       x, ea, ei, W1, b1, W2, b2, W3, b3, (const int*)nullptr, 1, out, n_edges);
  }
}